// Round 8
// baseline (233.337 us; speedup 1.0000x reference)
//
#include <hip/hip_runtime.h>
#include <hip/hip_bf16.h>

typedef __attribute__((ext_vector_type(8))) short short8;
typedef __attribute__((ext_vector_type(4))) float f32x4;

#define DEV static __device__ __forceinline__

DEV unsigned short f2bf(float f) {
  union { float f; unsigned u; } v; v.f = f;
  unsigned r = v.u + 0x7FFFu + ((v.u >> 16) & 1u);
  return (unsigned short)(r >> 16);
}
DEV float bf2f(unsigned short b) {
  union { unsigned u; float f; } v; v.u = ((unsigned)b) << 16;
  return v.f;
}

DEV unsigned cvtpk_bf16(float lo, float hi) {
  unsigned r;
  asm("v_cvt_pk_bf16_f32 %0, %1, %2" : "=v"(r) : "v"(lo), "v"(hi));
  return r;
}

DEV void gld_lds16(const void* g, void* l) {
  __builtin_amdgcn_global_load_lds(
      (const __attribute__((address_space(1))) unsigned int*)g,
      (__attribute__((address_space(3))) unsigned int*)l, 16, 0, 0);
}

DEV short8 lds_read8(const unsigned short* base, int byteoff) {
  return *reinterpret_cast<const short8*>(reinterpret_cast<const char*>(base) + byteoff);
}

// ---------------- cast x (fp32 -> bf16) ----------------
__global__ __launch_bounds__(256) void cast_x_kernel(const float* __restrict__ x,
                                                     unsigned short* __restrict__ xb, int n4) {
  int i = blockIdx.x * blockDim.x + threadIdx.x;
  if (i >= n4) return;
  float4 v = reinterpret_cast<const float4*>(x)[i];
  ushort4 o;
  o.x = f2bf(v.x); o.y = f2bf(v.y); o.z = f2bf(v.z); o.w = f2bf(v.w);
  reinterpret_cast<ushort4*>(xb)[i] = o;
}

// ---------------- mask -> packed bytes (0/1), linear layout ----------------
__global__ __launch_bounds__(256) void mask_prep_kernel(const int* __restrict__ mask,
                                                        unsigned char* __restrict__ mb) {
  int i = blockIdx.x * 256 + threadIdx.x;  // 2M groups of 4 k
  int4 m4 = reinterpret_cast<const int4*>(mask)[i];
  unsigned v = (m4.x ? 1u : 0u) | ((m4.y ? 1u : 0u) << 8) |
               ((m4.z ? 1u : 0u) << 16) | ((m4.w ? 1u : 0u) << 24);
  reinterpret_cast<unsigned*>(mb)[i] = v;
}

// ---------------- transpose + cast weights: W (512k x 512n) fp32 -> Wt (512n x 512k) bf16 ----------------
__global__ __launch_bounds__(256) void transpose_w_kernel(
    const float* __restrict__ W0, const float* __restrict__ W1,
    const float* __restrict__ W2, const float* __restrict__ W3,
    unsigned short* __restrict__ T0, unsigned short* __restrict__ T1,
    unsigned short* __restrict__ T2, unsigned short* __restrict__ T3) {
  const float* W = blockIdx.z == 0 ? W0 : blockIdx.z == 1 ? W1 : blockIdx.z == 2 ? W2 : W3;
  unsigned short* T = blockIdx.z == 0 ? T0 : blockIdx.z == 1 ? T1 : blockIdx.z == 2 ? T2 : T3;
  __shared__ unsigned short tile[32][33];
  int tx = threadIdx.x & 31, ty = threadIdx.x >> 5;
  int n0 = blockIdx.x * 32, k0 = blockIdx.y * 32;
#pragma unroll
  for (int i = 0; i < 32; i += 8)
    tile[ty + i][tx] = f2bf(W[(size_t)(k0 + ty + i) * 512 + n0 + tx]);
  __syncthreads();
#pragma unroll
  for (int i = 0; i < 32; i += 8)
    T[(size_t)(n0 + ty + i) * 512 + k0 + tx] = tile[tx][ty + i];
}

// ---------------- fused QKV projection GEMM ----------------
__global__ __launch_bounds__(256) void gemm_proj_kernel(
    const unsigned short* __restrict__ xb,
    const unsigned short* __restrict__ WqT, const unsigned short* __restrict__ WkT,
    const unsigned short* __restrict__ WvT,
    const float* __restrict__ bq, const float* __restrict__ bk, const float* __restrict__ bv,
    unsigned short* __restrict__ qn, unsigned short* __restrict__ kn,
    unsigned short* __restrict__ vn, unsigned short* __restrict__ vT) {
  const int z = blockIdx.z;
  const unsigned short* Wt = z == 0 ? WqT : z == 1 ? WkT : WvT;
  const float* bias = z == 0 ? bq : z == 1 ? bk : bv;
  unsigned short* outp = z == 0 ? qn : z == 1 ? kn : vn;

  __shared__ unsigned short smem[17408];
  unsigned short* As = smem;
  unsigned short* Bs = smem + 4096;

  const int tid = threadIdx.x;
  const int lane = tid & 63;
  const int w = tid >> 6;
  const int wm = w >> 1, wn = w & 1;
  const int lr = lane & 15;
  const int g = lane >> 4;

  const int m0 = blockIdx.x * 128;
  const int n0 = blockIdx.y * 128;

  f32x4 acc[4][4];
#pragma unroll
  for (int i = 0; i < 4; ++i)
#pragma unroll
    for (int j = 0; j < 4; ++j) acc[i][j] = (f32x4){0.f, 0.f, 0.f, 0.f};

  for (int kt = 0; kt < 16; ++kt) {
    const int k0 = kt * 32;
    __syncthreads();
#pragma unroll
    for (int p = 0; p < 2; ++p) {
      int slot = tid + 256 * p;
      int r = slot >> 2;
      int kg = (slot & 3) ^ ((r >> 1) & 3);
      unsigned short* ldsA = As + (size_t)((tid >> 6) + 4 * p) * 512;
      unsigned short* ldsB = Bs + (size_t)((tid >> 6) + 4 * p) * 512;
      gld_lds16(xb + (size_t)(m0 + r) * 512 + k0 + kg * 8, ldsA);
      gld_lds16(Wt + (size_t)(n0 + r) * 512 + k0 + kg * 8, ldsB);
    }
    __syncthreads();
    short8 af[4], bfr[4];
#pragma unroll
    for (int mi = 0; mi < 4; ++mi) {
      int r = wm * 64 + mi * 16 + lr;
      af[mi] = lds_read8(As, (r * 64 + g * 16) ^ (((r >> 1) & 3) << 4));
    }
#pragma unroll
    for (int ni = 0; ni < 4; ++ni) {
      int r = wn * 64 + ni * 16 + lr;
      bfr[ni] = lds_read8(Bs, (r * 64 + g * 16) ^ (((r >> 1) & 3) << 4));
    }
#pragma unroll
    for (int mi = 0; mi < 4; ++mi)
#pragma unroll
      for (int ni = 0; ni < 4; ++ni)
        acc[mi][ni] = __builtin_amdgcn_mfma_f32_16x16x32_bf16(af[mi], bfr[ni], acc[mi][ni], 0, 0, 0);
  }
  __syncthreads();

  float biasv[4];
#pragma unroll
  for (int ni = 0; ni < 4; ++ni) biasv[ni] = bias[n0 + wn * 64 + ni * 16 + lr];

#pragma unroll
  for (int mi = 0; mi < 4; ++mi) {
    int rowb = m0 + wm * 64 + mi * 16 + g * 4;
#pragma unroll
    for (int ni = 0; ni < 4; ++ni) {
      int c = n0 + wn * 64 + ni * 16 + lr;
      int h = c >> 6, d = c & 63;
#pragma unroll
      for (int rr = 0; rr < 4; ++rr) {
        float vf = acc[mi][ni][rr] + biasv[ni];
        vf = vf > 0.f ? vf : 0.f;
        unsigned short bvv = f2bf(vf);
        int row = rowb + rr;
        int b = row >> 10, tok = row & 1023;
        outp[((size_t)(b * 8 + h) * 1024 + tok) * 64 + d] = bvv;
        if (z == 2) {
          int cl = wn * 64 + ni * 16 + lr;
          int rl = wm * 64 + mi * 16 + g * 4 + rr;
          smem[cl * 136 + rl] = bvv;
        }
      }
    }
  }
  if (z == 2) {
    __syncthreads();
    int cl = tid >> 1, half = tid & 1;
    int gc = n0 + cl, h = gc >> 6, d = gc & 63;
    int b = m0 >> 10;
    int tokbase = (m0 & 1023) + half * 64;
    size_t base = (size_t)(b * 8 + h) * 65536 + (size_t)d * 1024 + tokbase;
    const unsigned short* src = smem + cl * 136 + half * 64;
#pragma unroll
    for (int j = 0; j < 8; ++j) {
      short8 v8 = *reinterpret_cast<const short8*>(src + j * 8);
      *reinterpret_cast<short8*>(vT + base + j * 8) = v8;
    }
  }
}

// ---------------- fused masked-softmax attention ----------------
// 2-phase dbuf pipeline, counted vmcnt(8) drain, XCD remap (b = bid&7).
// grid 512; per block 4 waves x 32 q-rows (128 q/block), KV tiles of 64.
// Per-tile compute (32 MFMA + softmax) > stage latency -> prefetch fully hides.
__global__ __launch_bounds__(256) void attn_kernel(
    const unsigned short* __restrict__ qg, const unsigned short* __restrict__ kgp,
    const unsigned short* __restrict__ vg, const unsigned short* __restrict__ vTg,
    const unsigned char* __restrict__ mb, float* __restrict__ attw,
    unsigned short* __restrict__ Og) {
  __shared__ unsigned short Ks[2][4096];  // [buf][64 kk][64 d], swizzled by kk&7
  __shared__ unsigned short Vs[2][4096];  // [buf][64 d][64 kk], swizzled by d&7
  __shared__ unsigned short Ps[8192];     // per-wave [32 q][64 kk], swizzled by q&7

  const int tid = threadIdx.x, lane = tid & 63, w = tid >> 6;
  const int lr = lane & 15, g = lane >> 4;

  // XCD-aware decode: b = bid&7 -> all 64 blocks of batch b co-locate on one XCD.
  const int bid = blockIdx.x;
  const int b = bid & 7;
  const int idx = bid >> 3;
  const int h = idx >> 3;
  const int qc = idx & 7;
  const int bh = b * 8 + h;

  const int qw = qc * 128 + w * 32;
  const size_t qbase = (size_t)bh * 65536;

  const unsigned short* kbase = kgp + qbase;
  const unsigned short* vbase = vTg + qbase;

  // staging geometry: per thread 2 chunks each of K,V; chunk (w+4p): row (w+4p)*8 + lane/8
  const int srow0 = w * 8 + (lane >> 3);
  const int sseg = lane & 7;

  // Q fragments (B-operand of swapped QK^T), 2 mi x 2 dc
  short8 aq[2][2];
#pragma unroll
  for (int mi = 0; mi < 2; ++mi)
#pragma unroll
    for (int dc = 0; dc < 2; ++dc)
      aq[mi][dc] = *reinterpret_cast<const short8*>(
          qg + qbase + (size_t)(qw + mi * 16 + lr) * 64 + dc * 32 + g * 8);

  f32x4 o[2][4];
#pragma unroll
  for (int mi = 0; mi < 2; ++mi)
#pragma unroll
    for (int di = 0; di < 4; ++di) o[mi][di] = (f32x4){0.f, 0.f, 0.f, 0.f};
  float lsum[2] = {0.f, 0.f};

  unsigned short* Pw = Ps + w * 2048;  // 32 rows x 128B
  const unsigned char* mp0 = mb + ((size_t)(b * 1024 + qw + lr)) * 1024 + g * 4;
  const unsigned char* mp1 = mp0 + 16 * 1024;
  float* awp0 = attw + ((size_t)bh * 1024 + qw + lr) * 1024 + g * 4;
  float* awp1 = awp0 + 16 * 1024;

  // prologue: stage tile 0 into buf 0
#pragma unroll
  for (int p = 0; p < 2; ++p) {
    int rr = srow0 + 32 * p;
    int sk = sseg ^ (rr & 7);
    gld_lds16(kbase + (size_t)rr * 64 + sk * 8, reinterpret_cast<char*>(Ks[0]) + (w + 4 * p) * 1024);
    gld_lds16(vbase + (size_t)rr * 1024 + sk * 8, reinterpret_cast<char*>(Vs[0]) + (w + 4 * p) * 1024);
  }
  asm volatile("s_waitcnt vmcnt(0)" ::: "memory");
  __builtin_amdgcn_sched_barrier(0);
  __builtin_amdgcn_s_barrier();

  int cur = 0;
  for (int t = 0; t < 16; ++t) {
    const int kv0 = t * 64;

    // mask loads FIRST (older than stage loads), non-temporal (read-once stream)
    unsigned mk[2][4];
#pragma unroll
    for (int mi = 0; mi < 2; ++mi)
#pragma unroll
      for (int ni = 0; ni < 4; ++ni)
        mk[mi][ni] = __builtin_nontemporal_load(reinterpret_cast<const unsigned*>(
            (mi ? mp1 : mp0) + kv0 + ni * 16));
    __builtin_amdgcn_sched_barrier(0);

    // stage next tile into alternate buffer
    if (t < 15) {
      const int kn0 = kv0 + 64;
      unsigned short* Kn = Ks[cur ^ 1];
      unsigned short* Vn = Vs[cur ^ 1];
#pragma unroll
      for (int p = 0; p < 2; ++p) {
        int rr = srow0 + 32 * p;
        int sk = sseg ^ (rr & 7);
        gld_lds16(kbase + (size_t)(kn0 + rr) * 64 + sk * 8,
                  reinterpret_cast<char*>(Kn) + (w + 4 * p) * 1024);
        gld_lds16(vbase + (size_t)rr * 1024 + kn0 + sk * 8,
                  reinterpret_cast<char*>(Vn) + (w + 4 * p) * 1024);
      }
    }
    __builtin_amdgcn_sched_barrier(0);

    const unsigned short* Kc = Ks[cur];
    const unsigned short* Vc = Vs[cur];

    // S^T = mfma(K, Q): s[mi][ni][rr] holds kk = kv0+ni*16+g*4+rr, q = qw+mi*16+lr
    // K fragment shared across both mi.
    f32x4 s[2][4];
    __builtin_amdgcn_s_setprio(1);
#pragma unroll
    for (int ni = 0; ni < 4; ++ni) {
      int row = ni * 16 + lr;
      s[0][ni] = (f32x4){0.f, 0.f, 0.f, 0.f};
      s[1][ni] = (f32x4){0.f, 0.f, 0.f, 0.f};
#pragma unroll
      for (int dc = 0; dc < 2; ++dc) {
        short8 ak = lds_read8(Kc, (row * 128 + dc * 64 + g * 16) ^ ((row & 7) << 4));
        s[0][ni] = __builtin_amdgcn_mfma_f32_16x16x32_bf16(ak, aq[0][dc], s[0][ni], 0, 0, 0);
        s[1][ni] = __builtin_amdgcn_mfma_f32_16x16x32_bf16(ak, aq[1][dc], s[1][ni], 0, 0, 0);
      }
    }
    __builtin_amdgcn_s_setprio(0);

    // attw nt-stores + mask + exp(sv-16) + P pack to wave-private LDS
#pragma unroll
    for (int mi = 0; mi < 2; ++mi)
#pragma unroll
      for (int ni = 0; ni < 4; ++ni) {
        f32x4 sv = s[mi][ni] * 0.125f;
        __builtin_nontemporal_store(
            sv, reinterpret_cast<f32x4*>((mi ? awp1 : awp0) + kv0 + ni * 16));
        unsigned m = mk[mi][ni];
        float p0 = (m & 0x000000FFu) ? __expf(sv[0] - 16.f) : 0.f;
        float p1 = (m & 0x0000FF00u) ? __expf(sv[1] - 16.f) : 0.f;
        float p2 = (m & 0x00FF0000u) ? __expf(sv[2] - 16.f) : 0.f;
        float p3 = (m & 0xFF000000u) ? __expf(sv[3] - 16.f) : 0.f;
        lsum[mi] += (p0 + p1) + (p2 + p3);
        uint2 pk = make_uint2(cvtpk_bf16(p0, p1), cvtpk_bf16(p2, p3));
        int pbyte = (mi * 2048 + lr * 128 + ni * 32 + g * 8) ^ ((lr & 7) << 4);
        *reinterpret_cast<uint2*>(reinterpret_cast<char*>(Pw) + pbyte) = pk;
      }

    // O += P @ V; V fragment shared across both mi
    __builtin_amdgcn_s_setprio(1);
#pragma unroll
    for (int kc = 0; kc < 2; ++kc) {
      short8 ap0 = lds_read8(Pw, (lr * 128 + kc * 64 + g * 16) ^ ((lr & 7) << 4));
      short8 ap1 = lds_read8(Pw, (2048 + lr * 128 + kc * 64 + g * 16) ^ ((lr & 7) << 4));
#pragma unroll
      for (int di = 0; di < 4; ++di) {
        int rd = di * 16 + lr;
        short8 bv8 = lds_read8(Vc, (rd * 128 + kc * 64 + g * 16) ^ ((rd & 7) << 4));
        o[0][di] = __builtin_amdgcn_mfma_f32_16x16x32_bf16(ap0, bv8, o[0][di], 0, 0, 0);
        o[1][di] = __builtin_amdgcn_mfma_f32_16x16x32_bf16(ap1, bv8, o[1][di], 0, 0, 0);
      }
    }
    __builtin_amdgcn_s_setprio(0);

    // COUNTED drain: only the 4 stage loads must retire; the 8 newest vmem ops
    // (attw dwordx4 nt-stores) may stay in flight across the barrier.
    asm volatile("s_waitcnt vmcnt(8)" ::: "memory");
    __builtin_amdgcn_sched_barrier(0);
    __builtin_amdgcn_s_barrier();
    __builtin_amdgcn_sched_barrier(0);
    cur ^= 1;
  }

  // end-of-kernel row-sum reduce + epilogue
#pragma unroll
  for (int mi = 0; mi < 2; ++mi) {
    float l = lsum[mi];
    l += __shfl_xor(l, 16);
    l += __shfl_xor(l, 32);
#pragma unroll
    for (int rr = 0; rr < 4; ++rr) {
      int gq2 = qw + mi * 16 + g * 4 + rr;
      float lq = __shfl(l, g * 4 + rr);
      float inv = 1.f / lq;
#pragma unroll
      for (int di = 0; di < 4; ++di) {
        int gd = di * 16 + lr;
        float ov = o[mi][di][rr] * inv + bf2f(vg[qbase + (size_t)gq2 * 64 + gd]);
        Og[((size_t)(b * 1024 + gq2)) * 512 + h * 64 + gd] = f2bf(ov);
      }
    }
  }
}

// ---------------- final GEMM: out = relu(Og @ Wo + bo), fp32 out ----------------
__global__ __launch_bounds__(256) void gemm_out_kernel(
    const unsigned short* __restrict__ Ab, const unsigned short* __restrict__ WoT,
    const float* __restrict__ bo, float* __restrict__ outp) {
  __shared__ unsigned short smem[8192];
  unsigned short* As = smem;
  unsigned short* Bs = smem + 4096;

  const int tid = threadIdx.x;
  const int lane = tid & 63;
  const int w = tid >> 6;
  const int wm = w >> 1, wn = w & 1;
  const int lr = lane & 15;
  const int g = lane >> 4;
  const int m0 = blockIdx.x * 128;
  const int n0 = blockIdx.y * 128;

  f32x4 acc[4][4];
#pragma unroll
  for (int i = 0; i < 4; ++i)
#pragma unroll
    for (int j = 0; j < 4; ++j) acc[i][j] = (f32x4){0.f, 0.f, 0.f, 0.f};

  for (int kt = 0; kt < 16; ++kt) {
    const int k0 = kt * 32;
    __syncthreads();
#pragma unroll
    for (int p = 0; p < 2; ++p) {
      int slot = tid + 256 * p;
      int r = slot >> 2;
      int kg = (slot & 3) ^ ((r >> 1) & 3);
      unsigned short* ldsA = As + (size_t)((tid >> 6) + 4 * p) * 512;
      unsigned short* ldsB = Bs + (size_t)((tid >> 6) + 4 * p) * 512;
      gld_lds16(Ab + (size_t)(m0 + r) * 512 + k0 + kg * 8, ldsA);
      gld_lds16(WoT + (size_t)(n0 + r) * 512 + k0 + kg * 8, ldsB);
    }
    __syncthreads();
    short8 af[4], bfr[4];
#pragma unroll
    for (int mi = 0; mi < 4; ++mi) {
      int r = wm * 64 + mi * 16 + lr;
      af[mi] = lds_read8(As, (r * 64 + g * 16) ^ (((r >> 1) & 3) << 4));
    }
#pragma unroll
    for (int ni = 0; ni < 4; ++ni) {
      int r = wn * 64 + ni * 16 + lr;
      bfr[ni] = lds_read8(Bs, (r * 64 + g * 16) ^ (((r >> 1) & 3) << 4));
    }
#pragma unroll
    for (int mi = 0; mi < 4; ++mi)
#pragma unroll
      for (int ni = 0; ni < 4; ++ni)
        acc[mi][ni] = __builtin_amdgcn_mfma_f32_16x16x32_bf16(af[mi], bfr[ni], acc[mi][ni], 0, 0, 0);
  }

  float biasv[4];
#pragma unroll
  for (int ni = 0; ni < 4; ++ni) biasv[ni] = bo[n0 + wn * 64 + ni * 16 + lr];
#pragma unroll
  for (int mi = 0; mi < 4; ++mi) {
    int rowb = m0 + wm * 64 + mi * 16 + g * 4;
#pragma unroll
    for (int ni = 0; ni < 4; ++ni) {
      int c = n0 + wn * 64 + ni * 16 + lr;
#pragma unroll
      for (int rr = 0; rr < 4; ++rr) {
        float vf = acc[mi][ni][rr] + biasv[ni];
        outp[(size_t)(rowb + rr) * 512 + c] = vf > 0.f ? vf : 0.f;
      }
    }
  }
}

extern "C" void kernel_launch(void* const* d_in, const int* in_sizes, int n_in,
                              void* d_out, int out_size, void* d_ws, size_t ws_size,
                              hipStream_t stream) {
  const float* x = (const float*)d_in[0];
  const float* Wv = (const float*)d_in[1];
  const float* bv = (const float*)d_in[2];
  const float* Wk = (const float*)d_in[3];
  const float* bk = (const float*)d_in[4];
  const float* Wq = (const float*)d_in[5];
  const float* bq = (const float*)d_in[6];
  const float* Wo = (const float*)d_in[7];
  const float* bo = (const float*)d_in[8];
  const int* mask = (const int*)d_in[9];

  char* ws = (char*)d_ws;
  unsigned short* xb  = (unsigned short*)(ws);
  unsigned char*  mbb = (unsigned char*)(ws);  // overlays xb AFTER proj GEMM consumed it
  unsigned short* WqT = (unsigned short*)(ws + 8388608);
  unsigned short* WkT = (unsigned short*)(ws + 8912896);
  unsigned short* WvT = (unsigned short*)(ws + 9437184);
  unsigned short* WoT = (unsigned short*)(ws + 9961472);
  unsigned short* qn  = (unsigned short*)(ws + 10485760);
  unsigned short* kn  = (unsigned short*)(ws + 18874368);
  unsigned short* vn  = (unsigned short*)(ws + 27262976);
  unsigned short* vT  = (unsigned short*)(ws + 35651584);
  unsigned short* Og  = (unsigned short*)(ws + 44040192);

  float* outp = (float*)d_out;
  float* attw = (float*)d_out + 4194304;

  cast_x_kernel<<<4096, 256, 0, stream>>>(x, xb, 1048576);

  dim3 tg(16, 16, 4);
  transpose_w_kernel<<<tg, 256, 0, stream>>>(Wq, Wk, Wv, Wo, WqT, WkT, WvT, WoT);

  dim3 gp(64, 4, 3);
  gemm_proj_kernel<<<gp, 256, 0, stream>>>(xb, WqT, WkT, WvT, bq, bk, bv, qn, kn, vn, vT);

  // mask -> bytes (overwrites xb region; xb no longer needed)
  mask_prep_kernel<<<8192, 256, 0, stream>>>(mask, mbb);

  attn_kernel<<<512, 256, 0, stream>>>(qn, kn, vn, vT, mbb, attw, Og);

  dim3 go(64, 4);
  gemm_out_kernel<<<go, 256, 0, stream>>>(Og, WoT, bo, outp);
}

// Round 9
// 156.383 us; speedup vs baseline: 1.4921x; 1.4921x over previous
//
#include <hip/hip_runtime.h>
#include <hip/hip_bf16.h>

typedef __attribute__((ext_vector_type(8))) short short8;
typedef __attribute__((ext_vector_type(4))) float f32x4;

#define DEV static __device__ __forceinline__

DEV unsigned short f2bf(float f) {
  union { float f; unsigned u; } v; v.f = f;
  unsigned r = v.u + 0x7FFFu + ((v.u >> 16) & 1u);
  return (unsigned short)(r >> 16);
}
DEV float bf2f(unsigned short b) {
  union { unsigned u; float f; } v; v.u = ((unsigned)b) << 16;
  return v.f;
}

DEV unsigned cvtpk_bf16(float lo, float hi) {
  unsigned r;
  asm("v_cvt_pk_bf16_f32 %0, %1, %2" : "=v"(r) : "v"(lo), "v"(hi));
  return r;
}

DEV void gld_lds16(const void* g, void* l) {
  __builtin_amdgcn_global_load_lds(
      (const __attribute__((address_space(1))) unsigned int*)g,
      (__attribute__((address_space(3))) unsigned int*)l, 16, 0, 0);
}

DEV short8 lds_read8(const unsigned short* base, int byteoff) {
  return *reinterpret_cast<const short8*>(reinterpret_cast<const char*>(base) + byteoff);
}

// ---------------- cast x (fp32 -> bf16) ----------------
__global__ __launch_bounds__(256) void cast_x_kernel(const float* __restrict__ x,
                                                     unsigned short* __restrict__ xb, int n4) {
  int i = blockIdx.x * blockDim.x + threadIdx.x;
  if (i >= n4) return;
  float4 v = reinterpret_cast<const float4*>(x)[i];
  ushort4 o;
  o.x = f2bf(v.x); o.y = f2bf(v.y); o.z = f2bf(v.z); o.w = f2bf(v.w);
  reinterpret_cast<ushort4*>(xb)[i] = o;
}

// ---------------- mask -> packed bytes (0/1), linear layout ----------------
__global__ __launch_bounds__(256) void mask_prep_kernel(const int* __restrict__ mask,
                                                        unsigned char* __restrict__ mb) {
  int i = blockIdx.x * 256 + threadIdx.x;  // 2M groups of 4 k
  int4 m4 = reinterpret_cast<const int4*>(mask)[i];
  unsigned v = (m4.x ? 1u : 0u) | ((m4.y ? 1u : 0u) << 8) |
               ((m4.z ? 1u : 0u) << 16) | ((m4.w ? 1u : 0u) << 24);
  reinterpret_cast<unsigned*>(mb)[i] = v;
}

// ---------------- transpose + cast weights: W (512k x 512n) fp32 -> Wt (512n x 512k) bf16 ----------------
__global__ __launch_bounds__(256) void transpose_w_kernel(
    const float* __restrict__ W0, const float* __restrict__ W1,
    const float* __restrict__ W2, const float* __restrict__ W3,
    unsigned short* __restrict__ T0, unsigned short* __restrict__ T1,
    unsigned short* __restrict__ T2, unsigned short* __restrict__ T3) {
  const float* W = blockIdx.z == 0 ? W0 : blockIdx.z == 1 ? W1 : blockIdx.z == 2 ? W2 : W3;
  unsigned short* T = blockIdx.z == 0 ? T0 : blockIdx.z == 1 ? T1 : blockIdx.z == 2 ? T2 : T3;
  __shared__ unsigned short tile[32][33];
  int tx = threadIdx.x & 31, ty = threadIdx.x >> 5;
  int n0 = blockIdx.x * 32, k0 = blockIdx.y * 32;
#pragma unroll
  for (int i = 0; i < 32; i += 8)
    tile[ty + i][tx] = f2bf(W[(size_t)(k0 + ty + i) * 512 + n0 + tx]);
  __syncthreads();
#pragma unroll
  for (int i = 0; i < 32; i += 8)
    T[(size_t)(n0 + ty + i) * 512 + k0 + tx] = tile[tx][ty + i];
}

// ---------------- fused QKV projection GEMM ----------------
__global__ __launch_bounds__(256) void gemm_proj_kernel(
    const unsigned short* __restrict__ xb,
    const unsigned short* __restrict__ WqT, const unsigned short* __restrict__ WkT,
    const unsigned short* __restrict__ WvT,
    const float* __restrict__ bq, const float* __restrict__ bk, const float* __restrict__ bv,
    unsigned short* __restrict__ qn, unsigned short* __restrict__ kn,
    unsigned short* __restrict__ vn, unsigned short* __restrict__ vT) {
  const int z = blockIdx.z;
  const unsigned short* Wt = z == 0 ? WqT : z == 1 ? WkT : WvT;
  const float* bias = z == 0 ? bq : z == 1 ? bk : bv;
  unsigned short* outp = z == 0 ? qn : z == 1 ? kn : vn;

  __shared__ unsigned short smem[17408];
  unsigned short* As = smem;
  unsigned short* Bs = smem + 4096;

  const int tid = threadIdx.x;
  const int lane = tid & 63;
  const int w = tid >> 6;
  const int wm = w >> 1, wn = w & 1;
  const int lr = lane & 15;
  const int g = lane >> 4;

  const int m0 = blockIdx.x * 128;
  const int n0 = blockIdx.y * 128;

  f32x4 acc[4][4];
#pragma unroll
  for (int i = 0; i < 4; ++i)
#pragma unroll
    for (int j = 0; j < 4; ++j) acc[i][j] = (f32x4){0.f, 0.f, 0.f, 0.f};

  for (int kt = 0; kt < 16; ++kt) {
    const int k0 = kt * 32;
    __syncthreads();
#pragma unroll
    for (int p = 0; p < 2; ++p) {
      int slot = tid + 256 * p;
      int r = slot >> 2;
      int kg = (slot & 3) ^ ((r >> 1) & 3);
      unsigned short* ldsA = As + (size_t)((tid >> 6) + 4 * p) * 512;
      unsigned short* ldsB = Bs + (size_t)((tid >> 6) + 4 * p) * 512;
      gld_lds16(xb + (size_t)(m0 + r) * 512 + k0 + kg * 8, ldsA);
      gld_lds16(Wt + (size_t)(n0 + r) * 512 + k0 + kg * 8, ldsB);
    }
    __syncthreads();
    short8 af[4], bfr[4];
#pragma unroll
    for (int mi = 0; mi < 4; ++mi) {
      int r = wm * 64 + mi * 16 + lr;
      af[mi] = lds_read8(As, (r * 64 + g * 16) ^ (((r >> 1) & 3) << 4));
    }
#pragma unroll
    for (int ni = 0; ni < 4; ++ni) {
      int r = wn * 64 + ni * 16 + lr;
      bfr[ni] = lds_read8(Bs, (r * 64 + g * 16) ^ (((r >> 1) & 3) << 4));
    }
#pragma unroll
    for (int mi = 0; mi < 4; ++mi)
#pragma unroll
      for (int ni = 0; ni < 4; ++ni)
        acc[mi][ni] = __builtin_amdgcn_mfma_f32_16x16x32_bf16(af[mi], bfr[ni], acc[mi][ni], 0, 0, 0);
  }
  __syncthreads();

  float biasv[4];
#pragma unroll
  for (int ni = 0; ni < 4; ++ni) biasv[ni] = bias[n0 + wn * 64 + ni * 16 + lr];

#pragma unroll
  for (int mi = 0; mi < 4; ++mi) {
    int rowb = m0 + wm * 64 + mi * 16 + g * 4;
#pragma unroll
    for (int ni = 0; ni < 4; ++ni) {
      int c = n0 + wn * 64 + ni * 16 + lr;
      int h = c >> 6, d = c & 63;
#pragma unroll
      for (int rr = 0; rr < 4; ++rr) {
        float vf = acc[mi][ni][rr] + biasv[ni];
        vf = vf > 0.f ? vf : 0.f;
        unsigned short bvv = f2bf(vf);
        int row = rowb + rr;
        int b = row >> 10, tok = row & 1023;
        outp[((size_t)(b * 8 + h) * 1024 + tok) * 64 + d] = bvv;
        if (z == 2) {
          int cl = wn * 64 + ni * 16 + lr;
          int rl = wm * 64 + mi * 16 + g * 4 + rr;
          smem[cl * 136 + rl] = bvv;
        }
      }
    }
  }
  if (z == 2) {
    __syncthreads();
    int cl = tid >> 1, half = tid & 1;
    int gc = n0 + cl, h = gc >> 6, d = gc & 63;
    int b = m0 >> 10;
    int tokbase = (m0 & 1023) + half * 64;
    size_t base = (size_t)(b * 8 + h) * 65536 + (size_t)d * 1024 + tokbase;
    const unsigned short* src = smem + cl * 136 + half * 64;
#pragma unroll
    for (int j = 0; j < 8; ++j) {
      short8 v8 = *reinterpret_cast<const short8*>(src + j * 8);
      *reinterpret_cast<short8*>(vT + base + j * 8) = v8;
    }
  }
}

// ---------------- fused masked-softmax attention ----------------
// Wave-independent: 1 wave (64 threads) per block, 32 q-rows, KVBLK=32,
// wave-private double-buffered K/V LDS, ZERO barriers. Per-tile FIFO:
// [stage next (8 gld_lds), mask next (4 loads)] -> s_waitcnt vmcnt(12)
// guarantees current tile staged+mask ready; prev tile's 4 attw stores get a
// full tile of slack. XCD remap: b = bid&7. LDS 20KB -> 8 blocks/CU.
__global__ __launch_bounds__(64) void attn_kernel(
    const unsigned short* __restrict__ qg, const unsigned short* __restrict__ kgp,
    const unsigned short* __restrict__ vg, const unsigned short* __restrict__ vTg,
    const unsigned char* __restrict__ mb, float* __restrict__ attw,
    unsigned short* __restrict__ Og) {
  __shared__ unsigned short Ks[2][2048];  // [buf][32 kk][64 d], rows 128B, swizzled by kk&7
  __shared__ unsigned short Vs[2][2048];  // [buf][64 d][32 kk], rows 64B, linear
  __shared__ unsigned short Ps[2048];     // [32 q][128B rows] (kk in first 64B), swizzled by q&7

  const int lane = threadIdx.x;
  const int lr = lane & 15, g = lane >> 4;

  // XCD-aware decode: b = bid&7 -> all 256 blocks of batch b co-locate on one XCD
  // (K 1MB + V 1MB + mask 1MB + Q 1MB fit its 4MB L2).
  const int bid = blockIdx.x;
  const int b = bid & 7;
  const int idx = bid >> 3;
  const int h = idx >> 5;
  const int qc = idx & 31;
  const int bh = b * 8 + h;

  const int qw = qc * 32;
  const size_t qbase = (size_t)bh * 65536;

  const unsigned short* kbase = kgp + qbase;
  const unsigned short* vbase = vTg + qbase;

  // staging geometry (per tile of 32 kk):
  // K: 4 issues j, row r = j*8 + lane/8, seg = lane%8 (8 x 16B = 128B row), src swizzled
  // V: 4 issues j, row d = j*16 + lane/4, seg = lane%4 (4 x 16B = 64B row), linear
  const int krow = lane >> 3, kseg = lane & 7;
  const int vrow = lane >> 2, vseg = lane & 3;

  // Q fragments (B-operand of swapped QK^T), 2 mi x 2 dc
  short8 aq[2][2];
#pragma unroll
  for (int mi = 0; mi < 2; ++mi)
#pragma unroll
    for (int dc = 0; dc < 2; ++dc)
      aq[mi][dc] = *reinterpret_cast<const short8*>(
          qg + qbase + (size_t)(qw + mi * 16 + lr) * 64 + dc * 32 + g * 8);

  f32x4 o[2][4];
#pragma unroll
  for (int mi = 0; mi < 2; ++mi)
#pragma unroll
    for (int di = 0; di < 4; ++di) o[mi][di] = (f32x4){0.f, 0.f, 0.f, 0.f};
  float lsum[2] = {0.f, 0.f};

  const unsigned char* mp0 = mb + ((size_t)(b * 1024 + qw + lr)) * 1024 + g * 4;
  const unsigned char* mp1 = mp0 + 16 * 1024;
  float* awp0 = attw + ((size_t)bh * 1024 + qw + lr) * 1024 + g * 4;
  float* awp1 = awp0 + 16 * 1024;

#define STAGE_KV(kv0, buf)                                                              \
  {                                                                                     \
    _Pragma("unroll") for (int j = 0; j < 4; ++j) {                                     \
      int r = j * 8 + krow;                                                             \
      gld_lds16(kbase + (size_t)((kv0) + r) * 64 + (kseg ^ (r & 7)) * 8,                \
                reinterpret_cast<char*>(Ks[buf]) + j * 1024);                           \
    }                                                                                   \
    _Pragma("unroll") for (int j = 0; j < 4; ++j) {                                     \
      int d = j * 16 + vrow;                                                            \
      gld_lds16(vbase + (size_t)d * 1024 + (kv0) + vseg * 8,                            \
                reinterpret_cast<char*>(Vs[buf]) + j * 1024);                           \
    }                                                                                   \
  }

  // prologue: stage tile 0 + mask 0
  STAGE_KV(0, 0)
  unsigned mk[2][2];
#pragma unroll
  for (int mi = 0; mi < 2; ++mi)
#pragma unroll
    for (int ni = 0; ni < 2; ++ni)
      mk[mi][ni] = *reinterpret_cast<const unsigned*>((mi ? mp1 : mp0) + ni * 16);

  int cur = 0;
  for (int t = 0; t < 32; ++t) {
    const int kv0 = t * 32;
    const int kn0 = ((t + 1) & 31) * 32;

    // issue next tile's stage + mask (12 vmem ops)
    STAGE_KV(kn0, cur ^ 1)
    unsigned mkn[2][2];
#pragma unroll
    for (int mi = 0; mi < 2; ++mi)
#pragma unroll
      for (int ni = 0; ni < 2; ++ni)
        mkn[mi][ni] = *reinterpret_cast<const unsigned*>((mi ? mp1 : mp0) + kn0 + ni * 16);
    __builtin_amdgcn_sched_barrier(0);

    // wait: everything older than the 12 just-issued ops has retired
    // (current tile's stage+mask ready; prev tile's 4 stores drained)
    asm volatile("s_waitcnt vmcnt(12)" ::: "memory");
    __builtin_amdgcn_sched_barrier(0);

    const unsigned short* Kc = Ks[cur];
    const unsigned short* Vc = Vs[cur];

    // S^T = mfma(K, Q): s[mi][ni][rr] holds kk = kv0+ni*16+g*4+rr, q = qw+mi*16+lr
    f32x4 s[2][2];
    __builtin_amdgcn_s_setprio(1);
#pragma unroll
    for (int ni = 0; ni < 2; ++ni) {
      int row = ni * 16 + lr;
      s[0][ni] = (f32x4){0.f, 0.f, 0.f, 0.f};
      s[1][ni] = (f32x4){0.f, 0.f, 0.f, 0.f};
#pragma unroll
      for (int dc = 0; dc < 2; ++dc) {
        short8 ak = lds_read8(Kc, (row * 128 + dc * 64 + g * 16) ^ ((row & 7) << 4));
        s[0][ni] = __builtin_amdgcn_mfma_f32_16x16x32_bf16(ak, aq[0][dc], s[0][ni], 0, 0, 0);
        s[1][ni] = __builtin_amdgcn_mfma_f32_16x16x32_bf16(ak, aq[1][dc], s[1][ni], 0, 0, 0);
      }
    }
    __builtin_amdgcn_s_setprio(0);

    // attw stores + mask + exp(sv-16) + P pack to wave-private LDS
#pragma unroll
    for (int mi = 0; mi < 2; ++mi)
#pragma unroll
      for (int ni = 0; ni < 2; ++ni) {
        f32x4 sv = s[mi][ni] * 0.125f;
        *reinterpret_cast<f32x4*>((mi ? awp1 : awp0) + kv0 + ni * 16) = sv;
        unsigned m = mk[mi][ni];
        float p0 = (m & 0x000000FFu) ? __expf(sv[0] - 16.f) : 0.f;
        float p1 = (m & 0x0000FF00u) ? __expf(sv[1] - 16.f) : 0.f;
        float p2 = (m & 0x00FF0000u) ? __expf(sv[2] - 16.f) : 0.f;
        float p3 = (m & 0xFF000000u) ? __expf(sv[3] - 16.f) : 0.f;
        lsum[mi] += (p0 + p1) + (p2 + p3);
        uint2 pk = make_uint2(cvtpk_bf16(p0, p1), cvtpk_bf16(p2, p3));
        int row = mi * 16 + lr;
        int pbyte = (row * 128 + ni * 32 + g * 8) ^ ((row & 7) << 4);
        *reinterpret_cast<uint2*>(reinterpret_cast<char*>(Ps) + pbyte) = pk;
      }

    // O += P @ V (no rescale: fixed exp offset); V fragment shared across both mi
    __builtin_amdgcn_s_setprio(1);
    {
      short8 ap0 = lds_read8(Ps, ((lr)*128 + g * 16) ^ ((lr & 7) << 4));
      short8 ap1 = lds_read8(Ps, ((16 + lr) * 128 + g * 16) ^ (((16 + lr) & 7) << 4));
#pragma unroll
      for (int di = 0; di < 4; ++di) {
        int rd = di * 16 + lr;
        short8 bv8 = lds_read8(Vc, rd * 64 + g * 16);
        o[0][di] = __builtin_amdgcn_mfma_f32_16x16x32_bf16(ap0, bv8, o[0][di], 0, 0, 0);
        o[1][di] = __builtin_amdgcn_mfma_f32_16x16x32_bf16(ap1, bv8, o[1][di], 0, 0, 0);
      }
    }
    __builtin_amdgcn_s_setprio(0);

#pragma unroll
    for (int mi = 0; mi < 2; ++mi)
#pragma unroll
      for (int ni = 0; ni < 2; ++ni) mk[mi][ni] = mkn[mi][ni];
    cur ^= 1;
  }

  // end-of-kernel row-sum reduce + epilogue (O/l + V residual)
#pragma unroll
  for (int mi = 0; mi < 2; ++mi) {
    float l = lsum[mi];
    l += __shfl_xor(l, 16);
    l += __shfl_xor(l, 32);
#pragma unroll
    for (int rr = 0; rr < 4; ++rr) {
      int gq2 = qw + mi * 16 + g * 4 + rr;
      float lq = __shfl(l, g * 4 + rr);
      float inv = 1.f / lq;
#pragma unroll
      for (int di = 0; di < 4; ++di) {
        int gd = di * 16 + lr;
        float ov = o[mi][di][rr] * inv + bf2f(vg[qbase + (size_t)gq2 * 64 + gd]);
        Og[((size_t)(b * 1024 + gq2)) * 512 + h * 64 + gd] = f2bf(ov);
      }
    }
  }
}

// ---------------- final GEMM: out = relu(Og @ Wo + bo), fp32 out ----------------
__global__ __launch_bounds__(256) void gemm_out_kernel(
    const unsigned short* __restrict__ Ab, const unsigned short* __restrict__ WoT,
    const float* __restrict__ bo, float* __restrict__ outp) {
  __shared__ unsigned short smem[8192];
  unsigned short* As = smem;
  unsigned short* Bs = smem + 4096;

  const int tid = threadIdx.x;
  const int lane = tid & 63;
  const int w = tid >> 6;
  const int wm = w >> 1, wn = w & 1;
  const int lr = lane & 15;
  const int g = lane >> 4;
  const int m0 = blockIdx.x * 128;
  const int n0 = blockIdx.y * 128;

  f32x4 acc[4][4];
#pragma unroll
  for (int i = 0; i < 4; ++i)
#pragma unroll
    for (int j = 0; j < 4; ++j) acc[i][j] = (f32x4){0.f, 0.f, 0.f, 0.f};

  for (int kt = 0; kt < 16; ++kt) {
    const int k0 = kt * 32;
    __syncthreads();
#pragma unroll
    for (int p = 0; p < 2; ++p) {
      int slot = tid + 256 * p;
      int r = slot >> 2;
      int kg = (slot & 3) ^ ((r >> 1) & 3);
      unsigned short* ldsA = As + (size_t)((tid >> 6) + 4 * p) * 512;
      unsigned short* ldsB = Bs + (size_t)((tid >> 6) + 4 * p) * 512;
      gld_lds16(Ab + (size_t)(m0 + r) * 512 + k0 + kg * 8, ldsA);
      gld_lds16(WoT + (size_t)(n0 + r) * 512 + k0 + kg * 8, ldsB);
    }
    __syncthreads();
    short8 af[4], bfr[4];
#pragma unroll
    for (int mi = 0; mi < 4; ++mi) {
      int r = wm * 64 + mi * 16 + lr;
      af[mi] = lds_read8(As, (r * 64 + g * 16) ^ (((r >> 1) & 3) << 4));
    }
#pragma unroll
    for (int ni = 0; ni < 4; ++ni) {
      int r = wn * 64 + ni * 16 + lr;
      bfr[ni] = lds_read8(Bs, (r * 64 + g * 16) ^ (((r >> 1) & 3) << 4));
    }
#pragma unroll
    for (int mi = 0; mi < 4; ++mi)
#pragma unroll
      for (int ni = 0; ni < 4; ++ni)
        acc[mi][ni] = __builtin_amdgcn_mfma_f32_16x16x32_bf16(af[mi], bfr[ni], acc[mi][ni], 0, 0, 0);
  }

  float biasv[4];
#pragma unroll
  for (int ni = 0; ni < 4; ++ni) biasv[ni] = bo[n0 + wn * 64 + ni * 16 + lr];
#pragma unroll
  for (int mi = 0; mi < 4; ++mi) {
    int rowb = m0 + wm * 64 + mi * 16 + g * 4;
#pragma unroll
    for (int ni = 0; ni < 4; ++ni) {
      int c = n0 + wn * 64 + ni * 16 + lr;
#pragma unroll
      for (int rr = 0; rr < 4; ++rr) {
        float vf = acc[mi][ni][rr] + biasv[ni];
        outp[(size_t)(rowb + rr) * 512 + c] = vf > 0.f ? vf : 0.f;
      }
    }
  }
}

extern "C" void kernel_launch(void* const* d_in, const int* in_sizes, int n_in,
                              void* d_out, int out_size, void* d_ws, size_t ws_size,
                              hipStream_t stream) {
  const float* x = (const float*)d_in[0];
  const float* Wv = (const float*)d_in[1];
  const float* bv = (const float*)d_in[2];
  const float* Wk = (const float*)d_in[3];
  const float* bk = (const float*)d_in[4];
  const float* Wq = (const float*)d_in[5];
  const float* bq = (const float*)d_in[6];
  const float* Wo = (const float*)d_in[7];
  const float* bo = (const float*)d_in[8];
  const int* mask = (const int*)d_in[9];

  char* ws = (char*)d_ws;
  unsigned short* xb  = (unsigned short*)(ws);
  unsigned char*  mbb = (unsigned char*)(ws);  // overlays xb AFTER proj GEMM consumed it
  unsigned short* WqT = (unsigned short*)(ws + 8388608);
  unsigned short* WkT = (unsigned short*)(ws + 8912896);
  unsigned short* WvT = (unsigned short*)(ws + 9437184);
  unsigned short* WoT = (unsigned short*)(ws + 9961472);
  unsigned short* qn  = (unsigned short*)(ws + 10485760);
  unsigned short* kn  = (unsigned short*)(ws + 18874368);
  unsigned short* vn  = (unsigned short*)(ws + 27262976);
  unsigned short* vT  = (unsigned short*)(ws + 35651584);
  unsigned short* Og  = (unsigned short*)(ws + 44040192);

  float* outp = (float*)d_out;
  float* attw = (float*)d_out + 4194304;

  cast_x_kernel<<<4096, 256, 0, stream>>>(x, xb, 1048576);

  dim3 tg(16, 16, 4);
  transpose_w_kernel<<<tg, 256, 0, stream>>>(Wq, Wk, Wv, Wo, WqT, WkT, WvT, WoT);

  dim3 gp(64, 4, 3);
  gemm_proj_kernel<<<gp, 256, 0, stream>>>(xb, WqT, WkT, WvT, bq, bk, bv, qn, kn, vn, vT);

  // mask -> bytes (overwrites xb region; xb no longer needed)
  mask_prep_kernel<<<8192, 256, 0, stream>>>(mask, mbb);

  attn_kernel<<<2048, 64, 0, stream>>>(qn, kn, vn, vT, mbb, attw, Og);

  dim3 go(64, 4);
  gemm_out_kernel<<<go, 256, 0, stream>>>(Og, WoT, bo, outp);
}

// Round 10
// 132.636 us; speedup vs baseline: 1.7592x; 1.1790x over previous
//
#include <hip/hip_runtime.h>
#include <hip/hip_bf16.h>

typedef __attribute__((ext_vector_type(8))) short short8;
typedef __attribute__((ext_vector_type(4))) float f32x4;

#define DEV static __device__ __forceinline__

DEV unsigned short f2bf(float f) {
  union { float f; unsigned u; } v; v.f = f;
  unsigned r = v.u + 0x7FFFu + ((v.u >> 16) & 1u);
  return (unsigned short)(r >> 16);
}
DEV float bf2f(unsigned short b) {
  union { unsigned u; float f; } v; v.u = ((unsigned)b) << 16;
  return v.f;
}

DEV unsigned cvtpk_bf16(float lo, float hi) {
  unsigned r;
  asm("v_cvt_pk_bf16_f32 %0, %1, %2" : "=v"(r) : "v"(lo), "v"(hi));
  return r;
}

DEV void gld_lds16(const void* g, void* l) {
  __builtin_amdgcn_global_load_lds(
      (const __attribute__((address_space(1))) unsigned int*)g,
      (__attribute__((address_space(3))) unsigned int*)l, 16, 0, 0);
}

DEV short8 lds_read8(const unsigned short* base, int byteoff) {
  return *reinterpret_cast<const short8*>(reinterpret_cast<const char*>(base) + byteoff);
}

// ---------------- merged prep: cast x + transpose weights + (optional) mask pack ----------------
// grid: [0,4096) cast_x  [4096,5120) transpose  [5120,13312) mask pack
__global__ __launch_bounds__(256) void prep_kernel(
    const float* __restrict__ x, unsigned short* __restrict__ xb,
    const float* __restrict__ W0, const float* __restrict__ W1,
    const float* __restrict__ W2, const float* __restrict__ W3,
    unsigned short* __restrict__ T0, unsigned short* __restrict__ T1,
    unsigned short* __restrict__ T2, unsigned short* __restrict__ T3,
    const int* __restrict__ mask, unsigned char* __restrict__ mb) {
  __shared__ unsigned short tile[32][33];
  const int bid = blockIdx.x, tid = threadIdx.x;
  if (bid < 4096) {
    int i = bid * 256 + tid;
    float4 v = reinterpret_cast<const float4*>(x)[i];
    ushort4 o;
    o.x = f2bf(v.x); o.y = f2bf(v.y); o.z = f2bf(v.z); o.w = f2bf(v.w);
    reinterpret_cast<ushort4*>(xb)[i] = o;
  } else if (bid < 5120) {
    int r = bid - 4096;
    int z = r >> 8;
    r &= 255;
    const float* W = z == 0 ? W0 : z == 1 ? W1 : z == 2 ? W2 : W3;
    unsigned short* T = z == 0 ? T0 : z == 1 ? T1 : z == 2 ? T2 : T3;
    int tx = tid & 31, ty = tid >> 5;
    int n0 = (r & 15) * 32, k0 = (r >> 4) * 32;
#pragma unroll
    for (int i = 0; i < 32; i += 8)
      tile[ty + i][tx] = f2bf(W[(size_t)(k0 + ty + i) * 512 + n0 + tx]);
    __syncthreads();
#pragma unroll
    for (int i = 0; i < 32; i += 8)
      T[(size_t)(n0 + ty + i) * 512 + k0 + tx] = tile[tx][ty + i];
  } else {
    int i = (bid - 5120) * 256 + tid;
    int4 m4 = reinterpret_cast<const int4*>(mask)[i];
    unsigned v = (m4.x ? 1u : 0u) | ((m4.y ? 1u : 0u) << 8) |
                 ((m4.z ? 1u : 0u) << 16) | ((m4.w ? 1u : 0u) << 24);
    reinterpret_cast<unsigned*>(mb)[i] = v;
  }
}

// ---------------- standalone mask pack (fallback when ws too small; overlays xb) ----------------
__global__ __launch_bounds__(256) void mask_prep_kernel(const int* __restrict__ mask,
                                                        unsigned char* __restrict__ mb) {
  int i = blockIdx.x * 256 + threadIdx.x;
  int4 m4 = reinterpret_cast<const int4*>(mask)[i];
  unsigned v = (m4.x ? 1u : 0u) | ((m4.y ? 1u : 0u) << 8) |
               ((m4.z ? 1u : 0u) << 16) | ((m4.w ? 1u : 0u) << 24);
  reinterpret_cast<unsigned*>(mb)[i] = v;
}

// ---------------- fused QKV projection GEMM ----------------
__global__ __launch_bounds__(256) void gemm_proj_kernel(
    const unsigned short* __restrict__ xb,
    const unsigned short* __restrict__ WqT, const unsigned short* __restrict__ WkT,
    const unsigned short* __restrict__ WvT,
    const float* __restrict__ bq, const float* __restrict__ bk, const float* __restrict__ bv,
    unsigned short* __restrict__ qn, unsigned short* __restrict__ kn,
    unsigned short* __restrict__ vn, unsigned short* __restrict__ vT) {
  const int z = blockIdx.z;
  const unsigned short* Wt = z == 0 ? WqT : z == 1 ? WkT : WvT;
  const float* bias = z == 0 ? bq : z == 1 ? bk : bv;
  unsigned short* outp = z == 0 ? qn : z == 1 ? kn : vn;

  __shared__ unsigned short smem[17408];
  unsigned short* As = smem;
  unsigned short* Bs = smem + 4096;

  const int tid = threadIdx.x;
  const int lane = tid & 63;
  const int w = tid >> 6;
  const int wm = w >> 1, wn = w & 1;
  const int lr = lane & 15;
  const int g = lane >> 4;

  const int m0 = blockIdx.x * 128;
  const int n0 = blockIdx.y * 128;

  f32x4 acc[4][4];
#pragma unroll
  for (int i = 0; i < 4; ++i)
#pragma unroll
    for (int j = 0; j < 4; ++j) acc[i][j] = (f32x4){0.f, 0.f, 0.f, 0.f};

  for (int kt = 0; kt < 16; ++kt) {
    const int k0 = kt * 32;
    __syncthreads();
#pragma unroll
    for (int p = 0; p < 2; ++p) {
      int slot = tid + 256 * p;
      int r = slot >> 2;
      int kg = (slot & 3) ^ ((r >> 1) & 3);
      unsigned short* ldsA = As + (size_t)((tid >> 6) + 4 * p) * 512;
      unsigned short* ldsB = Bs + (size_t)((tid >> 6) + 4 * p) * 512;
      gld_lds16(xb + (size_t)(m0 + r) * 512 + k0 + kg * 8, ldsA);
      gld_lds16(Wt + (size_t)(n0 + r) * 512 + k0 + kg * 8, ldsB);
    }
    __syncthreads();
    short8 af[4], bfr[4];
#pragma unroll
    for (int mi = 0; mi < 4; ++mi) {
      int r = wm * 64 + mi * 16 + lr;
      af[mi] = lds_read8(As, (r * 64 + g * 16) ^ (((r >> 1) & 3) << 4));
    }
#pragma unroll
    for (int ni = 0; ni < 4; ++ni) {
      int r = wn * 64 + ni * 16 + lr;
      bfr[ni] = lds_read8(Bs, (r * 64 + g * 16) ^ (((r >> 1) & 3) << 4));
    }
#pragma unroll
    for (int mi = 0; mi < 4; ++mi)
#pragma unroll
      for (int ni = 0; ni < 4; ++ni)
        acc[mi][ni] = __builtin_amdgcn_mfma_f32_16x16x32_bf16(af[mi], bfr[ni], acc[mi][ni], 0, 0, 0);
  }
  __syncthreads();

  float biasv[4];
#pragma unroll
  for (int ni = 0; ni < 4; ++ni) biasv[ni] = bias[n0 + wn * 64 + ni * 16 + lr];

#pragma unroll
  for (int mi = 0; mi < 4; ++mi) {
    int rowb = m0 + wm * 64 + mi * 16 + g * 4;
#pragma unroll
    for (int ni = 0; ni < 4; ++ni) {
      int c = n0 + wn * 64 + ni * 16 + lr;
      int h = c >> 6, d = c & 63;
#pragma unroll
      for (int rr = 0; rr < 4; ++rr) {
        float vf = acc[mi][ni][rr] + biasv[ni];
        vf = vf > 0.f ? vf : 0.f;
        unsigned short bvv = f2bf(vf);
        int row = rowb + rr;
        int b = row >> 10, tok = row & 1023;
        outp[((size_t)(b * 8 + h) * 1024 + tok) * 64 + d] = bvv;
        if (z == 2) {
          int cl = wn * 64 + ni * 16 + lr;
          int rl = wm * 64 + mi * 16 + g * 4 + rr;
          smem[cl * 136 + rl] = bvv;
        }
      }
    }
  }
  if (z == 2) {
    __syncthreads();
    int cl = tid >> 1, half = tid & 1;
    int gc = n0 + cl, h = gc >> 6, d = gc & 63;
    int b = m0 >> 10;
    int tokbase = (m0 & 1023) + half * 64;
    size_t base = (size_t)(b * 8 + h) * 65536 + (size_t)d * 1024 + tokbase;
    const unsigned short* src = smem + cl * 136 + half * 64;
#pragma unroll
    for (int j = 0; j < 8; ++j) {
      short8 v8 = *reinterpret_cast<const short8*>(src + j * 8);
      *reinterpret_cast<short8*>(vT + base + j * 8) = v8;
    }
  }
}

// ---------------- fused masked-softmax attention ----------------
// 8 waves x 16 q-rows (128 q/block); grid 512 -> EXACTLY 2 blocks/CU resident,
// zero-remainder dispatch. Shared dbuf K/V staging (1 gld_lds each per thread
// per tile), counted vmcnt(4) drain, XCD remap b = bid&7. LDS 48KB.
__global__ __launch_bounds__(512) void attn_kernel(
    const unsigned short* __restrict__ qg, const unsigned short* __restrict__ kgp,
    const unsigned short* __restrict__ vg, const unsigned short* __restrict__ vTg,
    const unsigned char* __restrict__ mb, float* __restrict__ attw,
    unsigned short* __restrict__ Og) {
  __shared__ unsigned short Ks[2][4096];  // [buf][64 kk][64 d], swizzled by kk&7
  __shared__ unsigned short Vs[2][4096];  // [buf][64 d][64 kk], swizzled by d&7
  __shared__ unsigned short Ps[8192];     // per-wave [16 q][64 kk], swizzled by q&7

  const int tid = threadIdx.x, lane = tid & 63, w = tid >> 6;
  const int lr = lane & 15, g = lane >> 4;

  const int bid = blockIdx.x;
  const int b = bid & 7;          // XCD-pinned batch
  const int idx = bid >> 3;
  const int h = idx >> 3;
  const int qc = idx & 7;
  const int bh = b * 8 + h;

  const int qw = qc * 128 + w * 16;
  const size_t qbase = (size_t)bh * 65536;

  const unsigned short* kbase = kgp + qbase;
  const unsigned short* vbase = vTg + qbase;

  // staging: 8 waves cover 64 rows; wave w stages rows w*8..w*8+7 (1KB each of K,V)
  const int srow = w * 8 + (lane >> 3);
  const int ssw = ((lane & 7) ^ (srow & 7)) * 8;

  // Q fragment (B-operand of swapped QK^T)
  short8 aq[2];
#pragma unroll
  for (int dc = 0; dc < 2; ++dc)
    aq[dc] = *reinterpret_cast<const short8*>(
        qg + qbase + (size_t)(qw + lr) * 64 + dc * 32 + g * 8);

  f32x4 o[4];
#pragma unroll
  for (int di = 0; di < 4; ++di) o[di] = (f32x4){0.f, 0.f, 0.f, 0.f};
  float lsum = 0.f;

  unsigned short* Pw = Ps + w * 1024;  // 16 rows x 128B
  const unsigned char* mp = mb + ((size_t)(b * 1024 + qw + lr)) * 1024 + g * 4;
  float* awp = attw + ((size_t)bh * 1024 + qw + lr) * 1024 + g * 4;

  // prologue: stage tile 0 into buf 0
  gld_lds16(kbase + (size_t)srow * 64 + ssw, reinterpret_cast<char*>(Ks[0]) + w * 1024);
  gld_lds16(vbase + (size_t)srow * 1024 + ssw, reinterpret_cast<char*>(Vs[0]) + w * 1024);
  asm volatile("s_waitcnt vmcnt(0)" ::: "memory");
  __builtin_amdgcn_sched_barrier(0);
  __builtin_amdgcn_s_barrier();

  int cur = 0;
  for (int t = 0; t < 16; ++t) {
    const int kv0 = t * 64;

    // mask loads FIRST (older than stage -> consuming them never drains the prefetch)
    unsigned mk[4];
#pragma unroll
    for (int ni = 0; ni < 4; ++ni)
      mk[ni] = *reinterpret_cast<const unsigned*>(mp + kv0 + ni * 16);
    __builtin_amdgcn_sched_barrier(0);

    // stage next tile into alternate buffer (hides under this tile's compute)
    if (t < 15) {
      const int kn0 = kv0 + 64;
      gld_lds16(kbase + (size_t)(kn0 + srow) * 64 + ssw,
                reinterpret_cast<char*>(Ks[cur ^ 1]) + w * 1024);
      gld_lds16(vbase + (size_t)srow * 1024 + kn0 + ssw,
                reinterpret_cast<char*>(Vs[cur ^ 1]) + w * 1024);
    }
    __builtin_amdgcn_sched_barrier(0);

    const unsigned short* Kc = Ks[cur];
    const unsigned short* Vc = Vs[cur];

    // S^T = mfma(K, Q): s[ni][rr] holds kk = kv0+ni*16+g*4+rr, q = qw+lr
    f32x4 s[4];
    __builtin_amdgcn_s_setprio(1);
#pragma unroll
    for (int ni = 0; ni < 4; ++ni) {
      int row = ni * 16 + lr;
      s[ni] = (f32x4){0.f, 0.f, 0.f, 0.f};
#pragma unroll
      for (int dc = 0; dc < 2; ++dc) {
        short8 ak = lds_read8(Kc, (row * 128 + dc * 64 + g * 16) ^ ((row & 7) << 4));
        s[ni] = __builtin_amdgcn_mfma_f32_16x16x32_bf16(ak, aq[dc], s[ni], 0, 0, 0);
      }
    }
    __builtin_amdgcn_s_setprio(0);

    // attw stores + mask + exp(sv-16) + P pack to wave-private LDS
#pragma unroll
    for (int ni = 0; ni < 4; ++ni) {
      f32x4 sv = s[ni] * 0.125f;
      *reinterpret_cast<f32x4*>(awp + kv0 + ni * 16) = sv;
      unsigned m = mk[ni];
      float p0 = (m & 0x000000FFu) ? __expf(sv[0] - 16.f) : 0.f;
      float p1 = (m & 0x0000FF00u) ? __expf(sv[1] - 16.f) : 0.f;
      float p2 = (m & 0x00FF0000u) ? __expf(sv[2] - 16.f) : 0.f;
      float p3 = (m & 0xFF000000u) ? __expf(sv[3] - 16.f) : 0.f;
      lsum += (p0 + p1) + (p2 + p3);
      uint2 pk = make_uint2(cvtpk_bf16(p0, p1), cvtpk_bf16(p2, p3));
      int pbyte = (lr * 128 + ni * 32 + g * 8) ^ ((lr & 7) << 4);
      *reinterpret_cast<uint2*>(reinterpret_cast<char*>(Pw) + pbyte) = pk;
    }

    // O += P @ V (no rescale: fixed exp offset)
    __builtin_amdgcn_s_setprio(1);
#pragma unroll
    for (int kc = 0; kc < 2; ++kc) {
      short8 ap = lds_read8(Pw, (lr * 128 + kc * 64 + g * 16) ^ ((lr & 7) << 4));
#pragma unroll
      for (int di = 0; di < 4; ++di) {
        int rd = di * 16 + lr;
        short8 bv8 = lds_read8(Vc, (rd * 128 + kc * 64 + g * 16) ^ ((rd & 7) << 4));
        o[di] = __builtin_amdgcn_mfma_f32_16x16x32_bf16(ap, bv8, o[di], 0, 0, 0);
      }
    }
    __builtin_amdgcn_s_setprio(0);

    // counted drain: 4 newest vmem ops (attw stores) may stay in flight
    asm volatile("s_waitcnt vmcnt(4)" ::: "memory");
    __builtin_amdgcn_sched_barrier(0);
    __builtin_amdgcn_s_barrier();
    __builtin_amdgcn_sched_barrier(0);
    cur ^= 1;
  }

  // single end-of-kernel row-sum reduce + epilogue (O/l + V residual)
  float l = lsum;
  l += __shfl_xor(l, 16);
  l += __shfl_xor(l, 32);

#pragma unroll
  for (int rr = 0; rr < 4; ++rr) {
    int gq2 = qw + g * 4 + rr;
    float lq = __shfl(l, g * 4 + rr);
    float inv = 1.f / lq;
#pragma unroll
    for (int di = 0; di < 4; ++di) {
      int gd = di * 16 + lr;
      float ov = o[di][rr] * inv + bf2f(vg[qbase + (size_t)gq2 * 64 + gd]);
      Og[((size_t)(b * 1024 + gq2)) * 512 + h * 64 + gd] = f2bf(ov);
    }
  }
}

// ---------------- final GEMM: out = relu(Og @ Wo + bo), fp32 out ----------------
__global__ __launch_bounds__(256) void gemm_out_kernel(
    const unsigned short* __restrict__ Ab, const unsigned short* __restrict__ WoT,
    const float* __restrict__ bo, float* __restrict__ outp) {
  __shared__ unsigned short smem[8192];
  unsigned short* As = smem;
  unsigned short* Bs = smem + 4096;

  const int tid = threadIdx.x;
  const int lane = tid & 63;
  const int w = tid >> 6;
  const int wm = w >> 1, wn = w & 1;
  const int lr = lane & 15;
  const int g = lane >> 4;
  const int m0 = blockIdx.x * 128;
  const int n0 = blockIdx.y * 128;

  f32x4 acc[4][4];
#pragma unroll
  for (int i = 0; i < 4; ++i)
#pragma unroll
    for (int j = 0; j < 4; ++j) acc[i][j] = (f32x4){0.f, 0.f, 0.f, 0.f};

  for (int kt = 0; kt < 16; ++kt) {
    const int k0 = kt * 32;
    __syncthreads();
#pragma unroll
    for (int p = 0; p < 2; ++p) {
      int slot = tid + 256 * p;
      int r = slot >> 2;
      int kg = (slot & 3) ^ ((r >> 1) & 3);
      unsigned short* ldsA = As + (size_t)((tid >> 6) + 4 * p) * 512;
      unsigned short* ldsB = Bs + (size_t)((tid >> 6) + 4 * p) * 512;
      gld_lds16(Ab + (size_t)(m0 + r) * 512 + k0 + kg * 8, ldsA);
      gld_lds16(WoT + (size_t)(n0 + r) * 512 + k0 + kg * 8, ldsB);
    }
    __syncthreads();
    short8 af[4], bfr[4];
#pragma unroll
    for (int mi = 0; mi < 4; ++mi) {
      int r = wm * 64 + mi * 16 + lr;
      af[mi] = lds_read8(As, (r * 64 + g * 16) ^ (((r >> 1) & 3) << 4));
    }
#pragma unroll
    for (int ni = 0; ni < 4; ++ni) {
      int r = wn * 64 + ni * 16 + lr;
      bfr[ni] = lds_read8(Bs, (r * 64 + g * 16) ^ (((r >> 1) & 3) << 4));
    }
#pragma unroll
    for (int mi = 0; mi < 4; ++mi)
#pragma unroll
      for (int ni = 0; ni < 4; ++ni)
        acc[mi][ni] = __builtin_amdgcn_mfma_f32_16x16x32_bf16(af[mi], bfr[ni], acc[mi][ni], 0, 0, 0);
  }

  float biasv[4];
#pragma unroll
  for (int ni = 0; ni < 4; ++ni) biasv[ni] = bo[n0 + wn * 64 + ni * 16 + lr];
#pragma unroll
  for (int mi = 0; mi < 4; ++mi) {
    int rowb = m0 + wm * 64 + mi * 16 + g * 4;
#pragma unroll
    for (int ni = 0; ni < 4; ++ni) {
      int c = n0 + wn * 64 + ni * 16 + lr;
#pragma unroll
      for (int rr = 0; rr < 4; ++rr) {
        float vf = acc[mi][ni][rr] + biasv[ni];
        outp[(size_t)(rowb + rr) * 512 + c] = vf > 0.f ? vf : 0.f;
      }
    }
  }
}

extern "C" void kernel_launch(void* const* d_in, const int* in_sizes, int n_in,
                              void* d_out, int out_size, void* d_ws, size_t ws_size,
                              hipStream_t stream) {
  const float* x = (const float*)d_in[0];
  const float* Wv = (const float*)d_in[1];
  const float* bv = (const float*)d_in[2];
  const float* Wk = (const float*)d_in[3];
  const float* bk = (const float*)d_in[4];
  const float* Wq = (const float*)d_in[5];
  const float* bq = (const float*)d_in[6];
  const float* Wo = (const float*)d_in[7];
  const float* bo = (const float*)d_in[8];
  const int* mask = (const int*)d_in[9];

  char* ws = (char*)d_ws;
  unsigned short* xb  = (unsigned short*)(ws);
  unsigned short* WqT = (unsigned short*)(ws + 8388608);
  unsigned short* WkT = (unsigned short*)(ws + 8912896);
  unsigned short* WvT = (unsigned short*)(ws + 9437184);
  unsigned short* WoT = (unsigned short*)(ws + 9961472);
  unsigned short* qn  = (unsigned short*)(ws + 10485760);
  unsigned short* kn  = (unsigned short*)(ws + 18874368);
  unsigned short* vn  = (unsigned short*)(ws + 27262976);
  unsigned short* vT  = (unsigned short*)(ws + 35651584);
  unsigned short* Og  = (unsigned short*)(ws + 44040192);

  // packed mask: above the main layout if ws permits (enables merged prep);
  // otherwise overlay xb and pack after the proj GEMM consumed it.
  const size_t MBB_HI = 52428800;
  const bool big = ws_size >= MBB_HI + 8388608;
  unsigned char* mbb = big ? (unsigned char*)(ws + MBB_HI) : (unsigned char*)ws;

  float* outp = (float*)d_out;
  float* attw = (float*)d_out + 4194304;

  prep_kernel<<<big ? 13312 : 5120, 256, 0, stream>>>(
      x, xb, Wq, Wk, Wv, Wo, WqT, WkT, WvT, WoT, mask, mbb);

  dim3 gp(64, 4, 3);
  gemm_proj_kernel<<<gp, 256, 0, stream>>>(xb, WqT, WkT, WvT, bq, bk, bv, qn, kn, vn, vT);

  if (!big) mask_prep_kernel<<<8192, 256, 0, stream>>>(mask, mbb);

  attn_kernel<<<512, 512, 0, stream>>>(qn, kn, vn, vT, mbb, attw, Og);

  dim3 go(64, 4);
  gemm_out_kernel<<<go, 256, 0, stream>>>(Og, WoT, bo, outp);
}

// Round 11
// 131.924 us; speedup vs baseline: 1.7687x; 1.0054x over previous
//
#include <hip/hip_runtime.h>
#include <hip/hip_bf16.h>

typedef __attribute__((ext_vector_type(8))) short short8;
typedef __attribute__((ext_vector_type(4))) float f32x4;

#define DEV static __device__ __forceinline__

DEV unsigned short f2bf(float f) {
  union { float f; unsigned u; } v; v.f = f;
  unsigned r = v.u + 0x7FFFu + ((v.u >> 16) & 1u);
  return (unsigned short)(r >> 16);
}
DEV float bf2f(unsigned short b) {
  union { unsigned u; float f; } v; v.u = ((unsigned)b) << 16;
  return v.f;
}

DEV unsigned cvtpk_bf16(float lo, float hi) {
  unsigned r;
  asm("v_cvt_pk_bf16_f32 %0, %1, %2" : "=v"(r) : "v"(lo), "v"(hi));
  return r;
}

DEV void gld_lds16(const void* g, void* l) {
  __builtin_amdgcn_global_load_lds(
      (const __attribute__((address_space(1))) unsigned int*)g,
      (__attribute__((address_space(3))) unsigned int*)l, 16, 0, 0);
}

DEV short8 lds_read8(const unsigned short* base, int byteoff) {
  return *reinterpret_cast<const short8*>(reinterpret_cast<const char*>(base) + byteoff);
}

// ---------------- merged prep: cast x + transpose weights + mask pack ----------------
// grid: [0,4096) cast_x  [4096,5120) transpose  [5120,13312) mask pack
__global__ __launch_bounds__(256) void prep_kernel(
    const float* __restrict__ x, unsigned short* __restrict__ xb,
    const float* __restrict__ W0, const float* __restrict__ W1,
    const float* __restrict__ W2, const float* __restrict__ W3,
    unsigned short* __restrict__ T0, unsigned short* __restrict__ T1,
    unsigned short* __restrict__ T2, unsigned short* __restrict__ T3,
    const int* __restrict__ mask, unsigned char* __restrict__ mb) {
  __shared__ unsigned short tile[32][33];
  const int bid = blockIdx.x, tid = threadIdx.x;
  if (bid < 4096) {
    int i = bid * 256 + tid;
    float4 v = reinterpret_cast<const float4*>(x)[i];
    ushort4 o;
    o.x = f2bf(v.x); o.y = f2bf(v.y); o.z = f2bf(v.z); o.w = f2bf(v.w);
    reinterpret_cast<ushort4*>(xb)[i] = o;
  } else if (bid < 5120) {
    int r = bid - 4096;
    int z = r >> 8;
    r &= 255;
    const float* W = z == 0 ? W0 : z == 1 ? W1 : z == 2 ? W2 : W3;
    unsigned short* T = z == 0 ? T0 : z == 1 ? T1 : z == 2 ? T2 : T3;
    int tx = tid & 31, ty = tid >> 5;
    int n0 = (r & 15) * 32, k0 = (r >> 4) * 32;
#pragma unroll
    for (int i = 0; i < 32; i += 8)
      tile[ty + i][tx] = f2bf(W[(size_t)(k0 + ty + i) * 512 + n0 + tx]);
    __syncthreads();
#pragma unroll
    for (int i = 0; i < 32; i += 8)
      T[(size_t)(n0 + ty + i) * 512 + k0 + tx] = tile[tx][ty + i];
  } else {
    int i = (bid - 5120) * 256 + tid;
    int4 m4 = reinterpret_cast<const int4*>(mask)[i];
    unsigned v = (m4.x ? 1u : 0u) | ((m4.y ? 1u : 0u) << 8) |
                 ((m4.z ? 1u : 0u) << 16) | ((m4.w ? 1u : 0u) << 24);
    reinterpret_cast<unsigned*>(mb)[i] = v;
  }
}

// ---------------- standalone mask pack (fallback when ws too small; overlays xb) ----------------
__global__ __launch_bounds__(256) void mask_prep_kernel(const int* __restrict__ mask,
                                                        unsigned char* __restrict__ mb) {
  int i = blockIdx.x * 256 + threadIdx.x;
  int4 m4 = reinterpret_cast<const int4*>(mask)[i];
  unsigned v = (m4.x ? 1u : 0u) | ((m4.y ? 1u : 0u) << 8) |
               ((m4.z ? 1u : 0u) << 16) | ((m4.w ? 1u : 0u) << 24);
  reinterpret_cast<unsigned*>(mb)[i] = v;
}

// ---------------- fused QKV projection GEMM (2-phase dbuf pipeline) ----------------
__global__ __launch_bounds__(256) void gemm_proj_kernel(
    const unsigned short* __restrict__ xb,
    const unsigned short* __restrict__ WqT, const unsigned short* __restrict__ WkT,
    const unsigned short* __restrict__ WvT,
    const float* __restrict__ bq, const float* __restrict__ bk, const float* __restrict__ bv,
    unsigned short* __restrict__ qn, unsigned short* __restrict__ kn,
    unsigned short* __restrict__ vn, unsigned short* __restrict__ vT) {
  const int z = blockIdx.z;
  const unsigned short* Wt = z == 0 ? WqT : z == 1 ? WkT : WvT;
  const float* bias = z == 0 ? bq : z == 1 ? bk : bv;
  unsigned short* outp = z == 0 ? qn : z == 1 ? kn : vn;

  // staging: As[2][4096] | Bs[2][4096] shorts (32KB); reused as [128][136] transpose tile
  __shared__ unsigned short smem[17408];
  unsigned short* As = smem;
  unsigned short* Bs = smem + 8192;

  const int tid = threadIdx.x;
  const int lane = tid & 63;
  const int w = tid >> 6;
  const int wm = w >> 1, wn = w & 1;
  const int lr = lane & 15;
  const int g = lane >> 4;

  const int m0 = blockIdx.x * 128;
  const int n0 = blockIdx.y * 128;

  f32x4 acc[4][4];
#pragma unroll
  for (int i = 0; i < 4; ++i)
#pragma unroll
    for (int j = 0; j < 4; ++j) acc[i][j] = (f32x4){0.f, 0.f, 0.f, 0.f};

#define STAGE_AB(buf, k0)                                                         \
  {                                                                               \
    _Pragma("unroll") for (int p = 0; p < 2; ++p) {                               \
      int slot = tid + 256 * p;                                                   \
      int r = slot >> 2;                                                          \
      int kg = (slot & 3) ^ ((r >> 1) & 3);                                       \
      unsigned short* ldsA = As + (buf)*4096 + (size_t)(w + 4 * p) * 512;         \
      unsigned short* ldsB = Bs + (buf)*4096 + (size_t)(w + 4 * p) * 512;         \
      gld_lds16(xb + (size_t)(m0 + r) * 512 + (k0) + kg * 8, ldsA);               \
      gld_lds16(Wt + (size_t)(n0 + r) * 512 + (k0) + kg * 8, ldsB);               \
    }                                                                             \
  }

  // prologue: stage k-step 0
  STAGE_AB(0, 0)
  asm volatile("s_waitcnt vmcnt(0)" ::: "memory");
  __builtin_amdgcn_sched_barrier(0);
  __builtin_amdgcn_s_barrier();

  int cur = 0;
  for (int kt = 0; kt < 16; ++kt) {
    // stage next K-step into alternate buffer (hides under this step's compute)
    if (kt < 15) STAGE_AB(cur ^ 1, (kt + 1) * 32)
    __builtin_amdgcn_sched_barrier(0);

    const unsigned short* Ac = As + cur * 4096;
    const unsigned short* Bc = Bs + cur * 4096;
    short8 af[4], bfr[4];
#pragma unroll
    for (int mi = 0; mi < 4; ++mi) {
      int r = wm * 64 + mi * 16 + lr;
      af[mi] = lds_read8(Ac, (r * 64 + g * 16) ^ (((r >> 1) & 3) << 4));
    }
#pragma unroll
    for (int ni = 0; ni < 4; ++ni) {
      int r = wn * 64 + ni * 16 + lr;
      bfr[ni] = lds_read8(Bc, (r * 64 + g * 16) ^ (((r >> 1) & 3) << 4));
    }
    __builtin_amdgcn_s_setprio(1);
#pragma unroll
    for (int mi = 0; mi < 4; ++mi)
#pragma unroll
      for (int ni = 0; ni < 4; ++ni)
        acc[mi][ni] = __builtin_amdgcn_mfma_f32_16x16x32_bf16(af[mi], bfr[ni], acc[mi][ni], 0, 0, 0);
    __builtin_amdgcn_s_setprio(0);

    asm volatile("s_waitcnt vmcnt(0)" ::: "memory");
    __builtin_amdgcn_sched_barrier(0);
    __builtin_amdgcn_s_barrier();
    __builtin_amdgcn_sched_barrier(0);
    cur ^= 1;
  }

  float biasv[4];
#pragma unroll
  for (int ni = 0; ni < 4; ++ni) biasv[ni] = bias[n0 + wn * 64 + ni * 16 + lr];

#pragma unroll
  for (int mi = 0; mi < 4; ++mi) {
    int rowb = m0 + wm * 64 + mi * 16 + g * 4;
#pragma unroll
    for (int ni = 0; ni < 4; ++ni) {
      int c = n0 + wn * 64 + ni * 16 + lr;
      int h = c >> 6, d = c & 63;
#pragma unroll
      for (int rr = 0; rr < 4; ++rr) {
        float vf = acc[mi][ni][rr] + biasv[ni];
        vf = vf > 0.f ? vf : 0.f;
        unsigned short bvv = f2bf(vf);
        int row = rowb + rr;
        int b = row >> 10, tok = row & 1023;
        outp[((size_t)(b * 8 + h) * 1024 + tok) * 64 + d] = bvv;
        if (z == 2) {
          int cl = wn * 64 + ni * 16 + lr;
          int rl = wm * 64 + mi * 16 + g * 4 + rr;
          smem[cl * 136 + rl] = bvv;
        }
      }
    }
  }
  if (z == 2) {
    __syncthreads();
    int cl = tid >> 1, half = tid & 1;
    int gc = n0 + cl, h = gc >> 6, d = gc & 63;
    int b = m0 >> 10;
    int tokbase = (m0 & 1023) + half * 64;
    size_t base = (size_t)(b * 8 + h) * 65536 + (size_t)d * 1024 + tokbase;
    const unsigned short* src = smem + cl * 136 + half * 64;
#pragma unroll
    for (int j = 0; j < 8; ++j) {
      short8 v8 = *reinterpret_cast<const short8*>(src + j * 8);
      *reinterpret_cast<short8*>(vT + base + j * 8) = v8;
    }
  }
#undef STAGE_AB
}

// ---------------- fused masked-softmax attention (unchanged from R10 best) ----------------
// 8 waves x 16 q-rows (128 q/block); grid 512 -> exactly 2 blocks/CU resident.
// Shared dbuf K/V staging, counted vmcnt(4) drain, XCD remap b = bid&7. LDS 48KB.
__global__ __launch_bounds__(512) void attn_kernel(
    const unsigned short* __restrict__ qg, const unsigned short* __restrict__ kgp,
    const unsigned short* __restrict__ vg, const unsigned short* __restrict__ vTg,
    const unsigned char* __restrict__ mb, float* __restrict__ attw,
    unsigned short* __restrict__ Og) {
  __shared__ unsigned short Ks[2][4096];  // [buf][64 kk][64 d], swizzled by kk&7
  __shared__ unsigned short Vs[2][4096];  // [buf][64 d][64 kk], swizzled by d&7
  __shared__ unsigned short Ps[8192];     // per-wave [16 q][64 kk], swizzled by q&7

  const int tid = threadIdx.x, lane = tid & 63, w = tid >> 6;
  const int lr = lane & 15, g = lane >> 4;

  const int bid = blockIdx.x;
  const int b = bid & 7;          // XCD-pinned batch
  const int idx = bid >> 3;
  const int h = idx >> 3;
  const int qc = idx & 7;
  const int bh = b * 8 + h;

  const int qw = qc * 128 + w * 16;
  const size_t qbase = (size_t)bh * 65536;

  const unsigned short* kbase = kgp + qbase;
  const unsigned short* vbase = vTg + qbase;

  const int srow = w * 8 + (lane >> 3);
  const int ssw = ((lane & 7) ^ (srow & 7)) * 8;

  short8 aq[2];
#pragma unroll
  for (int dc = 0; dc < 2; ++dc)
    aq[dc] = *reinterpret_cast<const short8*>(
        qg + qbase + (size_t)(qw + lr) * 64 + dc * 32 + g * 8);

  f32x4 o[4];
#pragma unroll
  for (int di = 0; di < 4; ++di) o[di] = (f32x4){0.f, 0.f, 0.f, 0.f};
  float lsum = 0.f;

  unsigned short* Pw = Ps + w * 1024;
  const unsigned char* mp = mb + ((size_t)(b * 1024 + qw + lr)) * 1024 + g * 4;
  float* awp = attw + ((size_t)bh * 1024 + qw + lr) * 1024 + g * 4;

  gld_lds16(kbase + (size_t)srow * 64 + ssw, reinterpret_cast<char*>(Ks[0]) + w * 1024);
  gld_lds16(vbase + (size_t)srow * 1024 + ssw, reinterpret_cast<char*>(Vs[0]) + w * 1024);
  asm volatile("s_waitcnt vmcnt(0)" ::: "memory");
  __builtin_amdgcn_sched_barrier(0);
  __builtin_amdgcn_s_barrier();

  int cur = 0;
  for (int t = 0; t < 16; ++t) {
    const int kv0 = t * 64;

    unsigned mk[4];
#pragma unroll
    for (int ni = 0; ni < 4; ++ni)
      mk[ni] = *reinterpret_cast<const unsigned*>(mp + kv0 + ni * 16);
    __builtin_amdgcn_sched_barrier(0);

    if (t < 15) {
      const int kn0 = kv0 + 64;
      gld_lds16(kbase + (size_t)(kn0 + srow) * 64 + ssw,
                reinterpret_cast<char*>(Ks[cur ^ 1]) + w * 1024);
      gld_lds16(vbase + (size_t)srow * 1024 + kn0 + ssw,
                reinterpret_cast<char*>(Vs[cur ^ 1]) + w * 1024);
    }
    __builtin_amdgcn_sched_barrier(0);

    const unsigned short* Kc = Ks[cur];
    const unsigned short* Vc = Vs[cur];

    f32x4 s[4];
    __builtin_amdgcn_s_setprio(1);
#pragma unroll
    for (int ni = 0; ni < 4; ++ni) {
      int row = ni * 16 + lr;
      s[ni] = (f32x4){0.f, 0.f, 0.f, 0.f};
#pragma unroll
      for (int dc = 0; dc < 2; ++dc) {
        short8 ak = lds_read8(Kc, (row * 128 + dc * 64 + g * 16) ^ ((row & 7) << 4));
        s[ni] = __builtin_amdgcn_mfma_f32_16x16x32_bf16(ak, aq[dc], s[ni], 0, 0, 0);
      }
    }
    __builtin_amdgcn_s_setprio(0);

#pragma unroll
    for (int ni = 0; ni < 4; ++ni) {
      f32x4 sv = s[ni] * 0.125f;
      *reinterpret_cast<f32x4*>(awp + kv0 + ni * 16) = sv;
      unsigned m = mk[ni];
      float p0 = (m & 0x000000FFu) ? __expf(sv[0] - 16.f) : 0.f;
      float p1 = (m & 0x0000FF00u) ? __expf(sv[1] - 16.f) : 0.f;
      float p2 = (m & 0x00FF0000u) ? __expf(sv[2] - 16.f) : 0.f;
      float p3 = (m & 0xFF000000u) ? __expf(sv[3] - 16.f) : 0.f;
      lsum += (p0 + p1) + (p2 + p3);
      uint2 pk = make_uint2(cvtpk_bf16(p0, p1), cvtpk_bf16(p2, p3));
      int pbyte = (lr * 128 + ni * 32 + g * 8) ^ ((lr & 7) << 4);
      *reinterpret_cast<uint2*>(reinterpret_cast<char*>(Pw) + pbyte) = pk;
    }

    __builtin_amdgcn_s_setprio(1);
#pragma unroll
    for (int kc = 0; kc < 2; ++kc) {
      short8 ap = lds_read8(Pw, (lr * 128 + kc * 64 + g * 16) ^ ((lr & 7) << 4));
#pragma unroll
      for (int di = 0; di < 4; ++di) {
        int rd = di * 16 + lr;
        short8 bv8 = lds_read8(Vc, (rd * 128 + kc * 64 + g * 16) ^ ((rd & 7) << 4));
        o[di] = __builtin_amdgcn_mfma_f32_16x16x32_bf16(ap, bv8, o[di], 0, 0, 0);
      }
    }
    __builtin_amdgcn_s_setprio(0);

    asm volatile("s_waitcnt vmcnt(4)" ::: "memory");
    __builtin_amdgcn_sched_barrier(0);
    __builtin_amdgcn_s_barrier();
    __builtin_amdgcn_sched_barrier(0);
    cur ^= 1;
  }

  float l = lsum;
  l += __shfl_xor(l, 16);
  l += __shfl_xor(l, 32);

#pragma unroll
  for (int rr = 0; rr < 4; ++rr) {
    int gq2 = qw + g * 4 + rr;
    float lq = __shfl(l, g * 4 + rr);
    float inv = 1.f / lq;
#pragma unroll
    for (int di = 0; di < 4; ++di) {
      int gd = di * 16 + lr;
      float ov = o[di][rr] * inv + bf2f(vg[qbase + (size_t)gq2 * 64 + gd]);
      Og[((size_t)(b * 1024 + gq2)) * 512 + h * 64 + gd] = f2bf(ov);
    }
  }
}

// ---------------- final GEMM: out = relu(Og @ Wo + bo), fp32 out (2-phase dbuf) ----------------
__global__ __launch_bounds__(256) void gemm_out_kernel(
    const unsigned short* __restrict__ Ab, const unsigned short* __restrict__ WoT,
    const float* __restrict__ bo, float* __restrict__ outp) {
  __shared__ unsigned short smem[16384];
  unsigned short* As = smem;
  unsigned short* Bs = smem + 8192;

  const int tid = threadIdx.x;
  const int lane = tid & 63;
  const int w = tid >> 6;
  const int wm = w >> 1, wn = w & 1;
  const int lr = lane & 15;
  const int g = lane >> 4;
  const int m0 = blockIdx.x * 128;
  const int n0 = blockIdx.y * 128;

  f32x4 acc[4][4];
#pragma unroll
  for (int i = 0; i < 4; ++i)
#pragma unroll
    for (int j = 0; j < 4; ++j) acc[i][j] = (f32x4){0.f, 0.f, 0.f, 0.f};

#define STAGE_AB(buf, k0)                                                         \
  {                                                                               \
    _Pragma("unroll") for (int p = 0; p < 2; ++p) {                               \
      int slot = tid + 256 * p;                                                   \
      int r = slot >> 2;                                                          \
      int kg = (slot & 3) ^ ((r >> 1) & 3);                                       \
      unsigned short* ldsA = As + (buf)*4096 + (size_t)(w + 4 * p) * 512;         \
      unsigned short* ldsB = Bs + (buf)*4096 + (size_t)(w + 4 * p) * 512;         \
      gld_lds16(Ab + (size_t)(m0 + r) * 512 + (k0) + kg * 8, ldsA);               \
      gld_lds16(WoT + (size_t)(n0 + r) * 512 + (k0) + kg * 8, ldsB);              \
    }                                                                             \
  }

  STAGE_AB(0, 0)
  asm volatile("s_waitcnt vmcnt(0)" ::: "memory");
  __builtin_amdgcn_sched_barrier(0);
  __builtin_amdgcn_s_barrier();

  int cur = 0;
  for (int kt = 0; kt < 16; ++kt) {
    if (kt < 15) STAGE_AB(cur ^ 1, (kt + 1) * 32)
    __builtin_amdgcn_sched_barrier(0);

    const unsigned short* Ac = As + cur * 4096;
    const unsigned short* Bc = Bs + cur * 4096;
    short8 af[4], bfr[4];
#pragma unroll
    for (int mi = 0; mi < 4; ++mi) {
      int r = wm * 64 + mi * 16 + lr;
      af[mi] = lds_read8(Ac, (r * 64 + g * 16) ^ (((r >> 1) & 3) << 4));
    }
#pragma unroll
    for (int ni = 0; ni < 4; ++ni) {
      int r = wn * 64 + ni * 16 + lr;
      bfr[ni] = lds_read8(Bc, (r * 64 + g * 16) ^ (((r >> 1) & 3) << 4));
    }
    __builtin_amdgcn_s_setprio(1);
#pragma unroll
    for (int mi = 0; mi < 4; ++mi)
#pragma unroll
      for (int ni = 0; ni < 4; ++ni)
        acc[mi][ni] = __builtin_amdgcn_mfma_f32_16x16x32_bf16(af[mi], bfr[ni], acc[mi][ni], 0, 0, 0);
    __builtin_amdgcn_s_setprio(0);

    asm volatile("s_waitcnt vmcnt(0)" ::: "memory");
    __builtin_amdgcn_sched_barrier(0);
    __builtin_amdgcn_s_barrier();
    __builtin_amdgcn_sched_barrier(0);
    cur ^= 1;
  }
#undef STAGE_AB

  float biasv[4];
#pragma unroll
  for (int ni = 0; ni < 4; ++ni) biasv[ni] = bo[n0 + wn * 64 + ni * 16 + lr];
#pragma unroll
  for (int mi = 0; mi < 4; ++mi) {
    int rowb = m0 + wm * 64 + mi * 16 + g * 4;
#pragma unroll
    for (int ni = 0; ni < 4; ++ni) {
      int c = n0 + wn * 64 + ni * 16 + lr;
#pragma unroll
      for (int rr = 0; rr < 4; ++rr) {
        float vf = acc[mi][ni][rr] + biasv[ni];
        outp[(size_t)(rowb + rr) * 512 + c] = vf > 0.f ? vf : 0.f;
      }
    }
  }
}

extern "C" void kernel_launch(void* const* d_in, const int* in_sizes, int n_in,
                              void* d_out, int out_size, void* d_ws, size_t ws_size,
                              hipStream_t stream) {
  const float* x = (const float*)d_in[0];
  const float* Wv = (const float*)d_in[1];
  const float* bv = (const float*)d_in[2];
  const float* Wk = (const float*)d_in[3];
  const float* bk = (const float*)d_in[4];
  const float* Wq = (const float*)d_in[5];
  const float* bq = (const float*)d_in[6];
  const float* Wo = (const float*)d_in[7];
  const float* bo = (const float*)d_in[8];
  const int* mask = (const int*)d_in[9];

  char* ws = (char*)d_ws;
  unsigned short* xb  = (unsigned short*)(ws);
  unsigned short* WqT = (unsigned short*)(ws + 8388608);
  unsigned short* WkT = (unsigned short*)(ws + 8912896);
  unsigned short* WvT = (unsigned short*)(ws + 9437184);
  unsigned short* WoT = (unsigned short*)(ws + 9961472);
  unsigned short* qn  = (unsigned short*)(ws + 10485760);
  unsigned short* kn  = (unsigned short*)(ws + 18874368);
  unsigned short* vn  = (unsigned short*)(ws + 27262976);
  unsigned short* vT  = (unsigned short*)(ws + 35651584);
  unsigned short* Og  = (unsigned short*)(ws + 44040192);

  const size_t MBB_HI = 52428800;
  const bool big = ws_size >= MBB_HI + 8388608;
  unsigned char* mbb = big ? (unsigned char*)(ws + MBB_HI) : (unsigned char*)ws;

  float* outp = (float*)d_out;
  float* attw = (float*)d_out + 4194304;

  prep_kernel<<<big ? 13312 : 5120, 256, 0, stream>>>(
      x, xb, Wq, Wk, Wv, Wo, WqT, WkT, WvT, WoT, mask, mbb);

  dim3 gp(64, 4, 3);
  gemm_proj_kernel<<<gp, 256, 0, stream>>>(xb, WqT, WkT, WvT, bq, bk, bv, qn, kn, vn, vT);

  if (!big) mask_prep_kernel<<<8192, 256, 0, stream>>>(mask, mbb);

  attn_kernel<<<512, 512, 0, stream>>>(qn, kn, vn, vT, mbb, attw, Og);

  dim3 go(64, 4);
  gemm_out_kernel<<<go, 256, 0, stream>>>(Og, WoT, bo, outp);
}